// Round 7
// baseline (344.115 us; speedup 1.0000x reference)
//
#include <hip/hip_runtime.h>

// Problem shape (fixed by reference): N=64, C=1024, H=W=28 -> HW=784
#define HWD 784
#define Q4  196            // HWD/4 float4 slots per channel row
#define CD  1024
#define ND  64

typedef float f32x4 __attribute__((ext_vector_type(4)));

// ---------------------------------------------------------------------------
// zeroS: S accumulator must be zeroed every call (ws is not re-poisoned).
// ---------------------------------------------------------------------------
__global__ void __launch_bounds__(1024) zeroS_kernel(float* __restrict__ S) {
    S[blockIdx.x * 1024 + threadIdx.x] = 0.0f;   // 49 blocks x 1024 = 50176
}

// ---------------------------------------------------------------------------
// K1': block = (n, 16-channel chunk), 1024 threads = 16 waves, 1 wave/channel.
// Contiguous 49KB cold read per block. Each wave:
//   - holds its full channel row (196 float4 across 64 lanes),
//   - butterfly-max -> thr = mu * max(relu(x*w)) (wave-local, no global thr),
//   - dropped = (cam > thr ? 0 : cam), LDS-atomic accumulate into S_block,
// then one global atomicAdd stream per block into S[n,784].
// The S-compute rides the mandatory 205MB cold read for free.
// ---------------------------------------------------------------------------
__global__ void __launch_bounds__(1024) sum_kernel(const float* __restrict__ x,
                                                   const float* __restrict__ w,
                                                   const float* __restrict__ mu_p,
                                                   float* __restrict__ S) {
    __shared__ float S_block[HWD];

    const int t = threadIdx.x;
    const int wave = t >> 6;
    const int lane = t & 63;
    const int n = blockIdx.y;
    const int c = blockIdx.x * 16 + wave;

    // zero the block accumulator
    if (t < HWD) S_block[t] = 0.0f;

    const float wc = w[c];
    const float4* row = reinterpret_cast<const float4*>(x + ((size_t)n * CD + c) * HWD);

    // load the wave's channel row: slots lane, lane+64, lane+128 (+192 for lanes 0-3)
    float4 v0 = row[lane];
    float4 v1 = row[lane + 64];
    float4 v2 = row[lane + 128];
    float4 v3 = (lane < 4) ? row[192 + lane] : float4{0.f, 0.f, 0.f, 0.f};

    // cam = relu(x*w); per-lane max
    float4 c0, c1, c2, c3;
    c0.x = fmaxf(v0.x * wc, 0.f); c0.y = fmaxf(v0.y * wc, 0.f);
    c0.z = fmaxf(v0.z * wc, 0.f); c0.w = fmaxf(v0.w * wc, 0.f);
    c1.x = fmaxf(v1.x * wc, 0.f); c1.y = fmaxf(v1.y * wc, 0.f);
    c1.z = fmaxf(v1.z * wc, 0.f); c1.w = fmaxf(v1.w * wc, 0.f);
    c2.x = fmaxf(v2.x * wc, 0.f); c2.y = fmaxf(v2.y * wc, 0.f);
    c2.z = fmaxf(v2.z * wc, 0.f); c2.w = fmaxf(v2.w * wc, 0.f);
    c3.x = fmaxf(v3.x * wc, 0.f); c3.y = fmaxf(v3.y * wc, 0.f);
    c3.z = fmaxf(v3.z * wc, 0.f); c3.w = fmaxf(v3.w * wc, 0.f);

    float m = fmaxf(fmaxf(fmaxf(c0.x, c0.y), fmaxf(c0.z, c0.w)),
                    fmaxf(fmaxf(c1.x, c1.y), fmaxf(c1.z, c1.w)));
    m = fmaxf(m, fmaxf(fmaxf(c2.x, c2.y), fmaxf(c2.z, c2.w)));
    m = fmaxf(m, fmaxf(fmaxf(c3.x, c3.y), fmaxf(c3.z, c3.w)));

    // wave-wide max (butterfly leaves result in all lanes)
    #pragma unroll
    for (int off = 32; off > 0; off >>= 1)
        m = fmaxf(m, __shfl_xor(m, off, 64));

    const float thr = m * mu_p[0];

    __syncthreads();   // S_block zeroed

    // dropped values -> LDS atomic accumulate (ds_add_f32, conflict-light)
    const int p0 = lane * 4;
    atomicAdd(&S_block[p0 + 0],       (c0.x > thr) ? 0.f : c0.x);
    atomicAdd(&S_block[p0 + 1],       (c0.y > thr) ? 0.f : c0.y);
    atomicAdd(&S_block[p0 + 2],       (c0.z > thr) ? 0.f : c0.z);
    atomicAdd(&S_block[p0 + 3],       (c0.w > thr) ? 0.f : c0.w);
    atomicAdd(&S_block[p0 + 256 + 0], (c1.x > thr) ? 0.f : c1.x);
    atomicAdd(&S_block[p0 + 256 + 1], (c1.y > thr) ? 0.f : c1.y);
    atomicAdd(&S_block[p0 + 256 + 2], (c1.z > thr) ? 0.f : c1.z);
    atomicAdd(&S_block[p0 + 256 + 3], (c1.w > thr) ? 0.f : c1.w);
    atomicAdd(&S_block[p0 + 512 + 0], (c2.x > thr) ? 0.f : c2.x);
    atomicAdd(&S_block[p0 + 512 + 1], (c2.y > thr) ? 0.f : c2.y);
    atomicAdd(&S_block[p0 + 512 + 2], (c2.z > thr) ? 0.f : c2.z);
    atomicAdd(&S_block[p0 + 512 + 3], (c2.w > thr) ? 0.f : c2.w);
    if (lane < 4) {
        atomicAdd(&S_block[p0 + 768 + 0], (c3.x > thr) ? 0.f : c3.x);
        atomicAdd(&S_block[p0 + 768 + 1], (c3.y > thr) ? 0.f : c3.y);
        atomicAdd(&S_block[p0 + 768 + 2], (c3.z > thr) ? 0.f : c3.z);
        atomicAdd(&S_block[p0 + 768 + 3], (c3.w > thr) ? 0.f : c3.w);
    }
    __syncthreads();

    // one global atomic stream per block
    if (t < HWD)
        atomicAdd(&S[n * HWD + t], S_block[t]);
}

// ---------------------------------------------------------------------------
// K2: pure streaming out = x * S. 3136 blocks x 256 thr x 16 iters covers
// all 12,845,056 float4 exactly. x read should be L3-hot (K1' just streamed
// it); NT store keeps the out stream from evicting x ahead of the reads.
// ---------------------------------------------------------------------------
__global__ void __launch_bounds__(256) mult_kernel(const float* __restrict__ x,
                                                   const float* __restrict__ S,
                                                   float* __restrict__ out) {
    const float4* x4 = reinterpret_cast<const float4*>(x);
    const float4* S4 = reinterpret_cast<const float4*>(S);

    int i4 = blockIdx.x * 256 + threadIdx.x;
    #pragma unroll 4
    for (int it = 0; it < 16; ++it, i4 += 3136 * 256) {
        const int r = i4 / Q4;                  // nc index (magic-mul)
        const int p4 = i4 - r * Q4;
        const int n = r >> 10;
        float4 xv = x4[i4];
        float4 sv = S4[n * Q4 + p4];
        float4 o;
        o.x = xv.x * sv.x;
        o.y = xv.y * sv.y;
        o.z = xv.z * sv.z;
        o.w = xv.w * sv.w;
        __builtin_nontemporal_store(*reinterpret_cast<const f32x4*>(&o),
                                    reinterpret_cast<f32x4*>(const_cast<float*>(out)) + i4);
    }
}

extern "C" void kernel_launch(void* const* d_in, const int* in_sizes, int n_in,
                              void* d_out, int out_size, void* d_ws, size_t ws_size,
                              hipStream_t stream) {
    const float* x  = (const float*)d_in[0];   // [N, C, H, W] f32
    const float* w  = (const float*)d_in[1];   // [C] f32
    const float* mu = (const float*)d_in[2];   // scalar (1-elem array)
    float* out = (float*)d_out;

    float* S = (float*)d_ws;                   // N*HWD floats (200 KB scratch)

    // zero the S accumulator (ws is not re-poisoned between replays)
    zeroS_kernel<<<ND * HWD / 1024, 1024, 0, stream>>>(S);

    // K1': 64 chunks x 64 samples, 1024 threads (16 waves = 16 channels)
    dim3 g1(CD / 16, ND);
    sum_kernel<<<g1, 1024, 0, stream>>>(x, w, mu, S);

    // K2: pure streaming multiply
    mult_kernel<<<3136, 256, 0, stream>>>(x, S, out);
}

// Round 8
// 99.625 us; speedup vs baseline: 3.4541x; 3.4541x over previous
//
#include <hip/hip_runtime.h>

// Problem shape (fixed by reference): N=64, C=1024, H=W=28 -> HW=784
#define HWD 784
#define Q4  196            // HWD/4 float4 slots per channel row
#define CD  1024
#define ND  64

#define CHPB 128           // channels per pass1 block
#define CHPW 8             // channels per wave (16 waves * 8 = 128)
#define NCHUNK (CD / CHPB) // 8 partial chunks

typedef float f32x4 __attribute__((ext_vector_type(4)));

__device__ __forceinline__ float4 cam4(float4 v, float wc) {
    float4 r;
    r.x = fmaxf(v.x * wc, 0.f);
    r.y = fmaxf(v.y * wc, 0.f);
    r.z = fmaxf(v.z * wc, 0.f);
    r.w = fmaxf(v.w * wc, 0.f);
    return r;
}
__device__ __forceinline__ float max4(float4 v) {
    return fmaxf(fmaxf(v.x, v.y), fmaxf(v.z, v.w));
}
__device__ __forceinline__ void accdrop(float4& a, float4 c, float thr) {
    a.x += (c.x > thr) ? 0.f : c.x;
    a.y += (c.y > thr) ? 0.f : c.y;
    a.z += (c.z > thr) ? 0.f : c.z;
    a.w += (c.w > thr) ? 0.f : c.w;
}

// ---------------------------------------------------------------------------
// Pass 1: block = (chunk of 128 channels, n). 1024 threads = 16 waves.
// Each wave: 8 consecutive channels, processed 2 at a time (8 float4 loads
// in flight). Per channel: wave-butterfly max -> thr, dropped values
// accumulated in REGISTERS (position-aligned). One LDS write per wave,
// one barrier, 16-way non-atomic cross-wave sum, one coalesced Spart store.
// S-compute rides the mandatory 205MB cold read. NO atomics.
// ---------------------------------------------------------------------------
__global__ void __launch_bounds__(1024) pass1_kernel(const float* __restrict__ x,
                                                     const float* __restrict__ w,
                                                     const float* __restrict__ mu_p,
                                                     float* __restrict__ Spart) {
    __shared__ float4 drp[16][197];   // wave stride 197*4=788 floats (%32=20)

    const int t = threadIdx.x;
    const int wave = t >> 6;
    const int lane = t & 63;
    const int n = blockIdx.y;
    const int cbase = blockIdx.x * CHPB + wave * CHPW;
    const float mu = mu_p[0];

    const float4* rows = reinterpret_cast<const float4*>(x + ((size_t)n * CD + cbase) * HWD);

    float4 acc0 = {0.f,0.f,0.f,0.f}, acc1 = {0.f,0.f,0.f,0.f};
    float4 acc2 = {0.f,0.f,0.f,0.f}, acc3 = {0.f,0.f,0.f,0.f};

    #pragma unroll 2
    for (int j = 0; j < CHPW / 2; ++j) {
        const float4* rA = rows + (2 * j) * Q4;
        const float4* rB = rA + Q4;
        // issue all 8 loads (6 full + 2 tail) before any compute
        float4 a0 = rA[lane], a1 = rA[lane + 64], a2 = rA[lane + 128];
        float4 b0 = rB[lane], b1 = rB[lane + 64], b2 = rB[lane + 128];
        float4 a3 = {0.f,0.f,0.f,0.f}, b3 = {0.f,0.f,0.f,0.f};
        if (lane < 4) { a3 = rA[192 + lane]; b3 = rB[192 + lane]; }

        const float wA = w[cbase + 2 * j];
        const float wB = w[cbase + 2 * j + 1];

        float4 cA0 = cam4(a0, wA), cA1 = cam4(a1, wA), cA2 = cam4(a2, wA), cA3 = cam4(a3, wA);
        float4 cB0 = cam4(b0, wB), cB1 = cam4(b1, wB), cB2 = cam4(b2, wB), cB3 = cam4(b3, wB);

        float mA = fmaxf(fmaxf(max4(cA0), max4(cA1)), fmaxf(max4(cA2), max4(cA3)));
        float mB = fmaxf(fmaxf(max4(cB0), max4(cB1)), fmaxf(max4(cB2), max4(cB3)));
        #pragma unroll
        for (int off = 32; off > 0; off >>= 1) {
            mA = fmaxf(mA, __shfl_xor(mA, off, 64));
            mB = fmaxf(mB, __shfl_xor(mB, off, 64));
        }
        const float thrA = mA * mu;
        const float thrB = mB * mu;

        accdrop(acc0, cA0, thrA); accdrop(acc1, cA1, thrA);
        accdrop(acc2, cA2, thrA); accdrop(acc3, cA3, thrA);   // zeros for lane>=4
        accdrop(acc0, cB0, thrB); accdrop(acc1, cB1, thrB);
        accdrop(acc2, cB2, thrB); accdrop(acc3, cB3, thrB);
    }

    drp[wave][lane]       = acc0;
    drp[wave][64 + lane]  = acc1;
    drp[wave][128 + lane] = acc2;
    if (lane < 4) drp[wave][192 + lane] = acc3;
    __syncthreads();

    if (t < HWD) {
        const float* f = reinterpret_cast<const float*>(&drp[0][0]);
        float s = 0.f;
        #pragma unroll
        for (int wv = 0; wv < 16; ++wv)
            s += f[wv * 788 + t];
        Spart[((size_t)blockIdx.x * ND + n) * HWD + t] = s;
    }
}

// ---------------------------------------------------------------------------
// Reduce: S[n,p] = sum over 8 chunks of Spart[chunk][n][p]. Coalesced.
// ---------------------------------------------------------------------------
__global__ void __launch_bounds__(256) reduce_kernel(const float* __restrict__ Spart,
                                                     float* __restrict__ S) {
    const int j = blockIdx.x * 256 + threadIdx.x;   // 0 .. 50175
    float s = 0.f;
    #pragma unroll
    for (int ch = 0; ch < NCHUNK; ++ch)
        s += Spart[(size_t)ch * ND * HWD + j];
    S[j] = s;
}

// ---------------------------------------------------------------------------
// Mult: pure streaming out = x * S. 3136 blocks x 256 thr x 16 iters covers
// all 12,845,056 float4 exactly (~45us measured in round 7). NT store keeps
// the out stream from evicting x.
// ---------------------------------------------------------------------------
__global__ void __launch_bounds__(256) mult_kernel(const float* __restrict__ x,
                                                   const float* __restrict__ S,
                                                   float* __restrict__ out) {
    const float4* x4 = reinterpret_cast<const float4*>(x);
    const float4* S4 = reinterpret_cast<const float4*>(S);

    int i4 = blockIdx.x * 256 + threadIdx.x;
    #pragma unroll 4
    for (int it = 0; it < 16; ++it, i4 += 3136 * 256) {
        const int r = i4 / Q4;                  // nc index (magic-mul)
        const int p4 = i4 - r * Q4;
        const int n = r >> 10;
        float4 xv = x4[i4];
        float4 sv = S4[n * Q4 + p4];
        float4 o;
        o.x = xv.x * sv.x;
        o.y = xv.y * sv.y;
        o.z = xv.z * sv.z;
        o.w = xv.w * sv.w;
        __builtin_nontemporal_store(*reinterpret_cast<const f32x4*>(&o),
                                    reinterpret_cast<f32x4*>(out) + i4);
    }
}

extern "C" void kernel_launch(void* const* d_in, const int* in_sizes, int n_in,
                              void* d_out, int out_size, void* d_ws, size_t ws_size,
                              hipStream_t stream) {
    const float* x  = (const float*)d_in[0];   // [N, C, H, W] f32
    const float* w  = (const float*)d_in[1];   // [C] f32
    const float* mu = (const float*)d_in[2];   // scalar (1-elem array)
    float* out = (float*)d_out;

    float* Spart = (float*)d_ws;                       // 8*64*784 = 1.6 MB
    float* S     = Spart + (size_t)NCHUNK * ND * HWD;  // 64*784 = 200 KB

    // Pass 1: 8 chunks x 64 samples, 1024 threads (16 waves x 8 channels)
    dim3 g1(NCHUNK, ND);
    pass1_kernel<<<g1, 1024, 0, stream>>>(x, w, mu, Spart);

    // Reduce: 50176 outputs
    reduce_kernel<<<ND * HWD / 256, 256, 0, stream>>>(Spart, S);

    // Mult: pure streaming multiply
    mult_kernel<<<3136, 256, 0, stream>>>(x, S, out);
}